// Round 9
// baseline (13.357 us; speedup 1.0000x reference)
//
#include <hip/hip_runtime.h>
#include <hip/hip_bf16.h>

#define T_LEN  4096
#define NLAG   5
#define CMAX   ((NLAG - 1) * 128 + 63)   // 575: max lag covered
#define ESTR   712                        // per-copy stride (bf16 elems), mult of 8
#define NRND   9                          // rounds 0..8; round p covers lags 64p..64p+63

typedef __attribute__((ext_vector_type(8))) short short8;
typedef __attribute__((ext_vector_type(4))) float f32x4;

static __device__ __forceinline__ unsigned short f2bf(float f) {
  __hip_bfloat16 h = __float2bfloat16(f);
  return *reinterpret_cast<unsigned short*>(&h);
}

#define CVT8(dst, va, vb) {                                                       \
    short8 _v;                                                                    \
    _v[0] = (short)f2bf((va).x); _v[1] = (short)f2bf((va).y);                     \
    _v[2] = (short)f2bf((va).z); _v[3] = (short)f2bf((va).w);                     \
    _v[4] = (short)f2bf((vb).x); _v[5] = (short)f2bf((vb).y);                     \
    _v[6] = (short)f2bf((vb).z); _v[7] = (short)f2bf((vb).w);                     \
    *reinterpret_cast<short8*>(dst) = _v; }

// Single launch. Waves 0-3: GEMM consumers; waves 4-7: A-staging producers.
// k-eval (d-eval) is INTERLEAVED with the GEMM j-loop: round p writes lags
// [64p, 64p+63]; COMPUTE(j) needs lags <= 63+128j i.e. rounds <= 2j; so
// rounds 2j+1, 2j+2 run inside iteration j (write range [128j+64,128j+191]
// is disjoint from COMPUTE(j)'s read range [128j-127,128j+63]).
__global__ __launch_bounds__(512) void ssm_one(
    const float* __restrict__ u, const float* __restrict__ rho,
    const float* __restrict__ theta, const float* __restrict__ br,
    const float* __restrict__ bi, const float* __restrict__ cr,
    const float* __restrict__ ci, float* __restrict__ out) {
  __shared__ __align__(16) unsigned short Ab[2][8192];     // 32 KB A dbuf
  __shared__ __align__(16) unsigned short E8[8 * ESTR];    // 11.1 KB rev-k copies
  __shared__ __align__(16) float pad[2][8][8][68];         // 34.8 KB dbuf reduce pad

  const int tid = threadIdx.x;
  const int lane = tid & 63;
  const int w = tid >> 6;                 // 0..7
  const bool prod = (w >= 4);
  const int pt = tid & 255;

  const int bid = blockIdx.x;             // 256 % 8 == 0 -> bijective XCD swizzle
  const int swz = (bid & 7) * 32 + (bid >> 3);
  const int t0 = (swz & 63) * 64;
  const int b0 = (swz >> 6) * 64;

  const int lrow = lane >> 4, lc16 = lane & 15;
  const float4 z4 = make_float4(0.f, 0.f, 0.f, 0.f);
  float4 av[2][4][2];
  f32x4 acc[2][2] = {};

#define ISSUEA(j, S) { _Pragma("unroll") for (int h_ = 0; h_ < 4; ++h_) {         \
    const int hh = pt + 256 * h_;                                                 \
    const int r_ = hh >> 4, cg = hh & 15;                                         \
    const int gg = t0 - (j) * 128 + cg * 8;                                       \
    if ((unsigned)gg < 4096u) {                                                   \
      const float* p_ = u + (size_t)(b0 + r_) * T_LEN + gg;                       \
      av[S][h_][0] = *reinterpret_cast<const float4*>(p_);                        \
      av[S][h_][1] = *reinterpret_cast<const float4*>(p_ + 4);                    \
    } else { av[S][h_][0] = z4; av[S][h_][1] = z4; } } }

#define WRITEA(buf, S) { _Pragma("unroll") for (int h_ = 0; h_ < 4; ++h_) {       \
    const int hh = pt + 256 * h_;                                                 \
    const int r_ = hh >> 4, cg = hh & 15;                                         \
    const int eo = r_ * 128 + ((cg * 8) ^ ((r_ & 7) << 3));                       \
    CVT8(&Ab[buf][eo], av[S][h_][0], av[S][h_][1]); } }

  if (prod) ISSUEA(0, 0);                 // A(0) HBM latency hides under prologue

  // ---- zero E8 (tail y>CMAX and the few unwritten slots must read 0) ----
  {
    const short8 z8 = {};
    for (int c = tid; c < ESTR; c += 512)
      *reinterpret_cast<short8*>(&E8[c * 8]) = z8;
  }

  // ---- per-mode params (lane = mode), lambda powers 0..8 and lam^64 ----
  const float rh = rho[lane], th = theta[lane];
  const float lr2 = -1.4426950408f * log1pf(expf(rh));       // log2 r
  const float rr_ = exp2f(lr2);
  const float lre = rr_ * __cosf(th), lim = rr_ * __sinf(th);
  const float brv = br[lane], biv = bi[lane];
  const float crv = cr[lane], civ = ci[lane];
  const float wre = crv * brv + civ * biv;                   // conj(c)*b
  const float wim = crv * biv - civ * brv;

  float Lr[9], Li[9];
  Lr[0] = 1.f; Li[0] = 0.f;
#pragma unroll
  for (int i = 1; i <= 8; ++i) {
    Lr[i] = Lr[i - 1] * lre - Li[i - 1] * lim;
    Li[i] = Lr[i - 1] * lim + Li[i - 1] * lre;
  }
  float L64r = Lr[8], L64i = Li[8];
#pragma unroll
  for (int q = 0; q < 3; ++q) {           // (lam^8)^(2^3) = lam^64
    const float nr = L64r * L64r - L64i * L64i;
    const float ni = 2.f * L64r * L64i;
    L64r = nr; L64i = ni;
  }

  // g = conj(c)b * lam^(8w): round p lag base = 64p + 8w
  const float d0f = (float)(8 * w);
  const float rd0 = exp2f(d0f * lr2);
  float f0 = d0f * (th * 0.15915494309f);
  f0 -= floorf(f0);
  const float a0 = 6.2831853072f * f0;
  const float c0 = __cosf(a0), s0 = __sinf(a0);
  float gr = rd0 * (wre * c0 - wim * s0);
  float gi = rd0 * (wre * s0 + wim * c0);

  const int r2 = lane >> 3, cc = lane & 7;

  // round rnd: this wave evaluates k_d for d = 64*rnd + 8*w + (0..7)
#define ROUND(rnd) {                                                              \
    float* mypad = &pad[(rnd) & 1][w][0][0];                                      \
    _Pragma("unroll") for (int i2 = 0; i2 < 8; ++i2)                              \
      mypad[i2 * 68 + lane] = gr * Lr[i2] - gi * Li[i2];     /* Re(g*lam^i2) */   \
    { const float ngr = gr * L64r - gi * L64i;                                    \
      const float ngi = gr * L64i + gi * L64r;                                    \
      gr = ngr; gi = ngi; }                                                       \
    const float4 p0 = *reinterpret_cast<const float4*>(&mypad[r2 * 68 + cc * 8]); \
    const float4 p1 = *reinterpret_cast<const float4*>(&mypad[r2 * 68 + cc * 8 + 4]); \
    float s_ = ((p0.x + p0.y) + (p0.z + p0.w)) + ((p1.x + p1.y) + (p1.z + p1.w)); \
    s_ += __shfl_xor(s_, 1); s_ += __shfl_xor(s_, 2); s_ += __shfl_xor(s_, 4);    \
    const int y_ = CMAX - (64 * (rnd) + 8 * w + r2);                              \
    if (y_ >= cc) E8[cc * ESTR + (y_ - cc)] = f2bf(s_); }

  __syncthreads();                        // E8 zeros visible before round stores
  ROUND(0);                               // lags 0..63: all COMPUTE(0) needs
  if (prod) { WRITEA(0, 0); ISSUEA(1, 1); }
  __syncthreads();                        // E8 rounds<=0 + Ab[0] ready

#define COMPUTE(jj, buf) {                                                        \
    const unsigned short* A = Ab[buf];                                            \
    const int wm = w >> 1, wn = w & 1;                                            \
    const int pB = 7 - (lc16 & 7);                                                \
    _Pragma("unroll") for (int ks = 0; ks < 4; ++ks) {                            \
      short8 af[2], bfr[2];                                                       \
      _Pragma("unroll") for (int ft = 0; ft < 2; ++ft) {                          \
        const int r = wm * 32 + ft * 16 + lc16;                                   \
        const int pe = (ks * 32 + lrow * 8) ^ ((r & 7) << 3);                     \
        af[ft] = *reinterpret_cast<const short8*>(&A[r * 128 + pe]); }            \
      _Pragma("unroll") for (int fn = 0; fn < 2; ++fn) {                          \
        const int rB = wn * 32 + fn * 16 + lc16;                                  \
        const int x0 = CMAX - (jj) * 128 - rB + ks * 32 + lrow * 8 - pB;          \
        bfr[fn] = *reinterpret_cast<const short8*>(&E8[pB * ESTR + x0]); }        \
      _Pragma("unroll") for (int ft = 0; ft < 2; ++ft)                            \
        _Pragma("unroll") for (int fn = 0; fn < 2; ++fn)                          \
          acc[ft][fn] = __builtin_amdgcn_mfma_f32_16x16x32_bf16(                  \
              af[ft], bfr[fn], acc[ft][fn], 0, 0, 0); } }

  // ---- fused loop: GEMM j + d-eval rounds 2j+1, 2j+2 (disjoint E8 ranges) ----
#pragma unroll
  for (int j = 0; j < NLAG; ++j) {
    if (prod) {
      if (j + 1 < NLAG) WRITEA((j + 1) & 1, (j + 1) & 1);
      if (j + 2 < NLAG) ISSUEA(j + 2, j & 1);
    } else {
      COMPUTE(j, j & 1);
    }
    if (2 * j + 1 < NRND) ROUND(2 * j + 1);
    if (2 * j + 2 < NRND) ROUND(2 * j + 2);
    if (j < NLAG - 1) __syncthreads();
  }

  // ---- epilogue (consumers only) ----
  if (!prod) {
    const int wm = w >> 1, wn = w & 1;
#pragma unroll
    for (int ft = 0; ft < 2; ++ft)
#pragma unroll
      for (int fn = 0; fn < 2; ++fn)
#pragma unroll
        for (int rg = 0; rg < 4; ++rg) {
          const int row = b0 + wm * 32 + ft * 16 + lrow * 4 + rg;
          const int col = t0 + wn * 32 + fn * 16 + lc16;
          out[(size_t)row * T_LEN + col] = acc[ft][fn][rg];
        }
  }
#undef ISSUEA
#undef WRITEA
#undef COMPUTE
#undef ROUND
}

extern "C" void kernel_launch(void* const* d_in, const int* in_sizes, int n_in,
                              void* d_out, int out_size, void* d_ws, size_t ws_size,
                              hipStream_t stream) {
  const float* u     = (const float*)d_in[0];
  const float* rho   = (const float*)d_in[1];
  const float* theta = (const float*)d_in[2];
  const float* br    = (const float*)d_in[3];
  const float* bi    = (const float*)d_in[4];
  const float* cr    = (const float*)d_in[5];
  const float* ci    = (const float*)d_in[6];
  float* out = (float*)d_out;

  ssm_one<<<256, 512, 0, stream>>>(u, rho, theta, br, bi, cr, ci, out);
}